// Round 3
// baseline (74.465 us; speedup 1.0000x reference)
//
#include <hip/hip_runtime.h>

// Problem constants (fixed by the reference)
#define C_TOT 160            // combined rows
#define R_    64
#define D_    4096
#define B_TOK 256
#define NENT  (C_TOT * R_)   // 10240
#define KS    8              // k-split for stage 1
#define NCAP  512            // per-token entry capacity in stage 2

typedef float float4v __attribute__((ext_vector_type(4)));

// Stage-1 partials, indexed [ks][lv_row*64 + r]; fully rewritten every call.
__device__ float g_lvp[KS][NENT];   // 320 KB

// ---------------------------------------------------------------------------
// S1: lv partials. grid = C_TOT*KS blocks, 256 threads (4 waves).
// lane = r -> lora_A reads are 256B wave-coalesced; x row read as float4.
// ---------------------------------------------------------------------------
__global__ __launch_bounds__(256) void s1(const float* __restrict__ A,
                                          const float* __restrict__ x,
                                          const int* __restrict__ xids,
                                          const int* __restrict__ wids) {
  const int b   = blockIdx.x;
  const int c   = b >> 3;            // combined row
  const int ks  = b & (KS - 1);      // k-split slice
  const int tid = threadIdx.x;
  const int r   = tid & 63;
  const int q   = tid >> 6;          // wave index: quarter of this slice
  const int w   = wids[c];
  const int tok = xids[c * R_ + r];

  const float* __restrict__ xrow = x + (size_t)tok * D_;
  const float* __restrict__ acol = A + (size_t)w * (D_ * R_) + r;

  const int k0 = ks * (D_ / KS) + q * (D_ / KS / 4);   // 128 k's per wave
  float acc = 0.f;
  #pragma unroll 4
  for (int k = k0; k < k0 + (D_ / KS / 4); k += 4) {
    const float4v xv = *reinterpret_cast<const float4v*>(xrow + k);
    acc = fmaf(xv[0], acol[(size_t)(k + 0) * R_], acc);
    acc = fmaf(xv[1], acol[(size_t)(k + 1) * R_], acc);
    acc = fmaf(xv[2], acol[(size_t)(k + 2) * R_], acc);
    acc = fmaf(xv[3], acol[(size_t)(k + 3) * R_], acc);
  }

  __shared__ float part[4][64];
  part[q][r] = acc;
  __syncthreads();
  if (tid < 64)
    g_lvp[ks][c * R_ + tid] =
        part[0][tid] + part[1][tid] + part[2][tid] + part[3][tid];
}

// ---------------------------------------------------------------------------
// S2: per-token gather. grid = B_TOK*2 blocks, 256 threads.
// Each block: one token, half of D (2048 f32 -> 8 acc / thread).
// Entries for this token found by a parallel filter over xids (L2-resident).
// ---------------------------------------------------------------------------
__global__ __launch_bounds__(256) void s2(const float* __restrict__ Bm,
                                          const int* __restrict__ xids,
                                          const int* __restrict__ wids,
                                          float* __restrict__ out) {
  const int t   = blockIdx.x >> 1;
  const int ch  = blockIdx.x & 1;
  const int tid = threadIdx.x;
  const int d0  = ch * 2048 + tid * 8;

  __shared__ int s_n;
  __shared__ int s_i[NCAP];
  if (tid == 0) s_n = 0;
  __syncthreads();
  for (int i = tid; i < NENT; i += 256) {
    if (xids[i] == t) {
      const int p = atomicAdd(&s_n, 1);
      if (p < NCAP) s_i[p] = i;
    }
  }
  __syncthreads();
  const int n = (s_n < NCAP) ? s_n : NCAP;

  float acc[8];
  #pragma unroll
  for (int e = 0; e < 8; ++e) acc[e] = 0.f;

  for (int j = 0; j < n; ++j) {
    const int i = s_i[j];
    const int c = i >> 6;
    const int r = i & 63;
    const int w = wids[c];
    const int idx = w * R_ + r;          // lv row = wids[c], col = r
    float cf = 0.f;
    #pragma unroll
    for (int p = 0; p < KS; ++p) cf += g_lvp[p][idx];
    const float* __restrict__ brow = Bm + (size_t)idx * D_ + d0;
    const float4v b0 = *reinterpret_cast<const float4v*>(brow);
    const float4v b1 = *reinterpret_cast<const float4v*>(brow + 4);
    acc[0] = fmaf(cf, b0[0], acc[0]);
    acc[1] = fmaf(cf, b0[1], acc[1]);
    acc[2] = fmaf(cf, b0[2], acc[2]);
    acc[3] = fmaf(cf, b0[3], acc[3]);
    acc[4] = fmaf(cf, b1[0], acc[4]);
    acc[5] = fmaf(cf, b1[1], acc[5]);
    acc[6] = fmaf(cf, b1[2], acc[6]);
    acc[7] = fmaf(cf, b1[3], acc[7]);
  }

  float* __restrict__ orow = out + (size_t)t * D_ + d0;
  float4v o0, o1;
  o0[0] = 2.0f * acc[0]; o0[1] = 2.0f * acc[1];
  o0[2] = 2.0f * acc[2]; o0[3] = 2.0f * acc[3];
  o1[0] = 2.0f * acc[4]; o1[1] = 2.0f * acc[5];
  o1[2] = 2.0f * acc[6]; o1[3] = 2.0f * acc[7];
  *reinterpret_cast<float4v*>(orow)     = o0;
  *reinterpret_cast<float4v*>(orow + 4) = o1;
}

// ---------------------------------------------------------------------------
extern "C" void kernel_launch(void* const* d_in, const int* in_sizes, int n_in,
                              void* d_out, int out_size, void* d_ws, size_t ws_size,
                              hipStream_t stream) {
  const float* lora_A = (const float*)d_in[0];
  const float* lora_B = (const float*)d_in[1];
  const float* x      = (const float*)d_in[2];
  const int* xids = (const int*)d_in[3];
  const int* wids = (const int*)d_in[4];
  float* out = (float*)d_out;

  hipLaunchKernelGGL(s1, dim3(C_TOT * KS), dim3(256), 0, stream,
                     lora_A, x, xids, wids);
  hipLaunchKernelGGL(s2, dim3(B_TOK * 2), dim3(256), 0, stream,
                     lora_B, xids, wids, out);
}

// Round 4
// 67.743 us; speedup vs baseline: 1.0992x; 1.0992x over previous
//
#include <hip/hip_runtime.h>

// Problem constants (fixed by the reference)
#define C_TOT 160            // combined rows (rows 128..159 of lv are never consumed)
#define C_USE 128            // lv rows actually consumable: wids[c] in [0,128)
#define R_    64
#define D_    4096
#define B_TOK 256
#define NENT  (C_TOT * R_)   // 10240 scatter entries
#define KS    8              // k-split for stage 1
#define LVN   (C_USE * R_)   // 8192 lv entries
#define NCAP  256            // per-token entry capacity (mean 40, max ~75)
#define CH    4              // D-chunks per token in stage 2

typedef float float4v __attribute__((ext_vector_type(4)));

// Scratch as device globals (capture-safe, rewritten every call).
__device__ float g_lvp[KS][LVN];   // stage-1 partials, 256 KB
__device__ float g_lv[LVN];        // reduced lv table, 32 KB

// ---------------------------------------------------------------------------
// S1: lv partials for c in [0,128). grid = C_USE*KS = 1024 blocks, 256 thr.
// lane = r -> lora_A reads are 256B wave-coalesced; x row read as float4.
// ---------------------------------------------------------------------------
__global__ __launch_bounds__(256) void s1(const float* __restrict__ A,
                                          const float* __restrict__ x,
                                          const int* __restrict__ xids,
                                          const int* __restrict__ wids) {
  const int b   = blockIdx.x;
  const int c   = b >> 3;            // lv row (== combined row), c < 128
  const int ks  = b & (KS - 1);      // k-split slice
  const int tid = threadIdx.x;
  const int r   = tid & 63;
  const int q   = tid >> 6;          // wave index: quarter of this slice
  const int w   = wids[c];
  const int tok = xids[c * R_ + r];

  const float* __restrict__ xrow = x + (size_t)tok * D_;
  const float* __restrict__ acol = A + (size_t)w * (D_ * R_) + r;

  const int k0 = ks * (D_ / KS) + q * (D_ / KS / 4);   // 128 k's per wave
  float acc = 0.f;
  #pragma unroll 4
  for (int k = k0; k < k0 + (D_ / KS / 4); k += 4) {
    const float4v xv = *reinterpret_cast<const float4v*>(xrow + k);
    acc = fmaf(xv[0], acol[(size_t)(k + 0) * R_], acc);
    acc = fmaf(xv[1], acol[(size_t)(k + 1) * R_], acc);
    acc = fmaf(xv[2], acol[(size_t)(k + 2) * R_], acc);
    acc = fmaf(xv[3], acol[(size_t)(k + 3) * R_], acc);
  }

  __shared__ float part[4][64];
  part[q][r] = acc;
  __syncthreads();
  if (tid < 64)
    g_lvp[ks][c * R_ + tid] =
        part[0][tid] + part[1][tid] + part[2][tid] + part[3][tid];
}

// ---------------------------------------------------------------------------
// S1R: collapse the 8 partials -> g_lv. grid = LVN/256 = 32 blocks.
// ---------------------------------------------------------------------------
__global__ __launch_bounds__(256) void s1r() {
  const int i = blockIdx.x * 256 + threadIdx.x;
  float s = 0.f;
  #pragma unroll
  for (int p = 0; p < KS; ++p) s += g_lvp[p][i];
  g_lv[i] = s;
}

// ---------------------------------------------------------------------------
// S2: per-token gather. grid = B_TOK*CH = 1024 blocks, 256 threads.
// Each block: one token, D/CH = 1024 floats (float4 per thread).
// Entry list found by a parallel filter over xids (L2-resident, 40 KB).
// ---------------------------------------------------------------------------
__global__ __launch_bounds__(256) void s2(const float* __restrict__ Bm,
                                          const int* __restrict__ xids,
                                          const int* __restrict__ wids,
                                          float* __restrict__ out) {
  const int t   = blockIdx.x >> 2;
  const int ch  = blockIdx.x & (CH - 1);
  const int tid = threadIdx.x;
  const int d0  = ch * (D_ / CH) + tid * 4;

  __shared__ int   s_n;
  __shared__ int   s_idx[NCAP];
  __shared__ float s_cf[NCAP];
  if (tid == 0) s_n = 0;
  __syncthreads();
  for (int i = tid; i < NENT; i += 256) {
    if (xids[i] == t) {
      const int p = atomicAdd(&s_n, 1);
      if (p < NCAP) s_idx[p] = wids[i >> 6] * R_ + (i & 63);  // lv/B row index
    }
  }
  __syncthreads();
  const int n = (s_n < NCAP) ? s_n : NCAP;
  if (tid < n) s_cf[tid] = g_lv[s_idx[tid]];
  __syncthreads();

  float4v acc;
  acc[0] = acc[1] = acc[2] = acc[3] = 0.f;

  for (int j = 0; j < n; ++j) {
    const int   idx = s_idx[j];
    const float cf  = s_cf[j];
    const float4v bv =
        *reinterpret_cast<const float4v*>(Bm + (size_t)idx * D_ + d0);
    acc[0] = fmaf(cf, bv[0], acc[0]);
    acc[1] = fmaf(cf, bv[1], acc[1]);
    acc[2] = fmaf(cf, bv[2], acc[2]);
    acc[3] = fmaf(cf, bv[3], acc[3]);
  }

  float4v o;
  o[0] = 2.0f * acc[0]; o[1] = 2.0f * acc[1];
  o[2] = 2.0f * acc[2]; o[3] = 2.0f * acc[3];
  *reinterpret_cast<float4v*>(out + (size_t)t * D_ + d0) = o;
}

// ---------------------------------------------------------------------------
extern "C" void kernel_launch(void* const* d_in, const int* in_sizes, int n_in,
                              void* d_out, int out_size, void* d_ws, size_t ws_size,
                              hipStream_t stream) {
  const float* lora_A = (const float*)d_in[0];
  const float* lora_B = (const float*)d_in[1];
  const float* x      = (const float*)d_in[2];
  const int* xids = (const int*)d_in[3];
  const int* wids = (const int*)d_in[4];
  float* out = (float*)d_out;

  hipLaunchKernelGGL(s1, dim3(C_USE * KS), dim3(256), 0, stream,
                     lora_A, x, xids, wids);
  hipLaunchKernelGGL(s1r, dim3(LVN / 256), dim3(256), 0, stream);
  hipLaunchKernelGGL(s2, dim3(B_TOK * CH), dim3(256), 0, stream,
                     lora_B, xids, wids, out);
}